// Round 6
// baseline (13082.152 us; speedup 1.0000x reference)
//
#include <hip/hip_runtime.h>

// QINCo fp32, round 6: R3's load:FMA ratio + 2x occupancy.
// k_step: 512 threads = two independent 256-thread halves, each owning 32 of
// the 64 candidate rows. Padded LDS (zero conflicts, R5-proven patterns):
// Z[64][132] + Hb[64][68] = 51.2KB -> 3 blocks/CU = 24 waves/CU (75% occ).
// Per-thread: 2 rows x 4 cols (GEMM1: 2 LDS + 4 loads / 32 FMA),
//             2 rows x 8 cols (GEMM2: 2 LDS + 8 loads / 64 FMA).
// Shapes: D=128, M=8, K=256, L=2, H=256, BS=1024. All fp32.
// Out layout (floats): xhat[1024*128] | codes[1024*8] | side[8][1024*128]

#define OUT_CODES 131072
#define OUT_SIDE  139264

// ws float offsets
#define WS_XHAT  0          // [1024][128]
#define WS_RB    131072     // [1024][128]  r = x - xhat
#define WS_Y     262144     // [1024][128]  y = xhat @ Wx^T
#define WS_ZC    393216     // [256][128]   zc = cb + cb@Wz^T + bc
#define WS_BESTD 425984     // [1024][4]
#define WS_BESTI 430080     // [1024][4] (int)
#define WS_BESTZ 434176     // [1024][4][128]

#define ZP 132              // padded Z row stride (floats)
#define HP 68               // padded Hb row stride (floats)

// ---------------- step 0: nearest codebook0 row ----------------
__global__ __launch_bounds__(256) void k_step0(const float* __restrict__ x,
    const float* __restrict__ cb0, float* __restrict__ ws, float* __restrict__ out)
{
  __shared__ float xs[128];
  __shared__ float redv[4];
  __shared__ int   redi[4];
  __shared__ int   kwin;
  int tx = threadIdx.x, b = blockIdx.x;
  if (tx < 128) xs[tx] = x[b * 128 + tx];
  __syncthreads();
  const float* c = cb0 + tx * 128;   // k = tx
  float s = 0.f;
  for (int d = 0; d < 128; d += 4) {
    float4 cv = *(const float4*)(c + d);
    float4 xv = *(const float4*)(xs + d);
    float a0 = xv.x - cv.x, a1 = xv.y - cv.y, a2 = xv.z - cv.z, a3 = xv.w - cv.w;
    s += a0 * a0 + a1 * a1 + a2 * a2 + a3 * a3;
  }
  float v = s; int idx = tx;
  for (int off = 32; off; off >>= 1) {
    float v2 = __shfl_xor(v, off);
    int   i2 = __shfl_xor(idx, off);
    if (v2 < v || (v2 == v && i2 < idx)) { v = v2; idx = i2; }
  }
  if ((tx & 63) == 0) { redv[tx >> 6] = v; redi[tx >> 6] = idx; }
  __syncthreads();
  if (tx == 0) {
    float bv = redv[0]; int bi = redi[0];
    for (int w = 1; w < 4; w++)
      if (redv[w] < bv || (redv[w] == bv && redi[w] < bi)) { bv = redv[w]; bi = redi[w]; }
    kwin = bi;
    out[OUT_CODES + b * 8] = (float)bi;
  }
  __syncthreads();
  int k = kwin;
  if (tx < 128) {
    float xh = cb0[k * 128 + tx];
    ws[WS_XHAT + b * 128 + tx] = xh;
    ws[WS_RB   + b * 128 + tx] = xs[tx] - xh;
    out[OUT_SIDE + b * 128 + tx] = xh;   // side[0]
  }
}

// ---------------- per-step prep: zc and y ----------------
__global__ __launch_bounds__(128) void k_prep(const float* __restrict__ cb,
    const float* __restrict__ Wc, const float* __restrict__ bcm, float* __restrict__ ws)
{
  __shared__ float row[128];
  int tx = threadIdx.x, blk = blockIdx.x;
  if (blk < 256) {          // zc[k][i] = cb[k][i] + sum_d cb[k][d]*Wc[i][d] + bc[i]
    row[tx] = cb[blk * 128 + tx];
    __syncthreads();
    const float* wrow = Wc + tx * 256;
    float s = 0.f;
    for (int d = 0; d < 128; d += 4) {
      float4 wv = *(const float4*)(wrow + d);
      float4 zv = *(const float4*)(row + d);
      s += wv.x * zv.x + wv.y * zv.y + wv.z * zv.z + wv.w * zv.w;
    }
    ws[WS_ZC + blk * 128 + tx] = row[tx] + s + bcm[tx];
  } else {                  // y[b][i] = sum_d xhat[b][d]*Wc[i][128+d]
    int b = blk - 256;
    row[tx] = ws[WS_XHAT + b * 128 + tx];
    __syncthreads();
    const float* wrow = Wc + tx * 256 + 128;
    float s = 0.f;
    for (int d = 0; d < 128; d += 4) {
      float4 wv = *(const float4*)(wrow + d);
      float4 zv = *(const float4*)(row + d);
      s += wv.x * zv.x + wv.y * zv.y + wv.z * zv.z + wv.w * zv.w;
    }
    ws[WS_Y + b * 128 + tx] = s;
  }
}

// ---------------- main step kernel: 64 candidates of one b ----------------
// 512 threads; half = tx>>8 owns rows [32*half, 32*half+32).
// Within a half (u = tx&255): rg = u&15 -> rows {32h+rg, 32h+rg+16};
// cg = u>>4 (0..15): GEMM1 cols 4cg..4cg+3 (per 64-col hb block),
// GEMM2 out cols 8cg..8cg+7.
__global__ __launch_bounds__(512, 6) void k_step(const float* __restrict__ W1g,
    const float* __restrict__ W2g, float* __restrict__ ws, int m)
{
  __shared__ float Z[64 * ZP];
  __shared__ float Hb[64 * HP];
  int tx = threadIdx.x;
  int half = tx >> 8, u = tx & 255;
  int rg = u & 15, cg = u >> 4;
  int r0 = (half << 5) + rg;          // rows r0, r0+16
  int b = blockIdx.x >> 2, t = blockIdx.x & 3, k0 = t << 6;

  // init Z = zc[k0+r] + y[b]
  {
    const float* zc = ws + WS_ZC + k0 * 128;
    const float* y  = ws + WS_Y + b * 128;
    for (int i = tx; i < 2048; i += 512) {
      int r = i >> 5, dq = (i & 31) << 2;
      float4 zv = *(const float4*)(zc + r * 128 + dq);
      float4 yv = *(const float4*)(y + dq);
      zv.x += yv.x; zv.y += yv.y; zv.z += yv.z; zv.w += yv.w;
      *(float4*)(Z + r * ZP + dq) = zv;
    }
  }
  __syncthreads();

  const float* Zr0 = Z + r0 * ZP;
  const float* Zr1 = Z + (r0 + 16) * ZP;
  float* Hw0 = Hb + r0 * HP + (cg << 2);
  float* Hw1 = Hb + (r0 + 16) * HP + (cg << 2);
  const float* Hr0 = Hb + r0 * HP;
  const float* Hr1 = Hb + (r0 + 16) * HP;

  for (int l = 0; l < 2; l++) {
    const float* w1l = W1g + (size_t)(m * 2 + l) * (256 * 128);
    const float* w2l = W2g + (size_t)(m * 2 + l) * (128 * 256);
    float accz[2][8];
#pragma unroll
    for (int i = 0; i < 2; i++)
#pragma unroll
      for (int q = 0; q < 8; q++) accz[i][q] = 0.f;

    for (int hb = 0; hb < 4; hb++) {
      // ---- GEMM1: a1[i][c] = sum_d Z[row_i][d] * W1[hb*64+4cg+c][d] ----
      float a1[2][4];
#pragma unroll
      for (int i = 0; i < 2; i++)
#pragma unroll
        for (int c = 0; c < 4; c++) a1[i][c] = 0.f;
      const float* w1b = w1l + (size_t)(hb * 64 + (cg << 2)) * 128;
      for (int d = 0; d < 128; d += 4) {
        float4 z0 = *(const float4*)(Zr0 + d);
        float4 z1 = *(const float4*)(Zr1 + d);
#pragma unroll
        for (int c = 0; c < 4; c++) {
          float4 wv = *(const float4*)(w1b + c * 128 + d);
          a1[0][c] = fmaf(z0.w, wv.w, fmaf(z0.z, wv.z, fmaf(z0.y, wv.y, fmaf(z0.x, wv.x, a1[0][c]))));
          a1[1][c] = fmaf(z1.w, wv.w, fmaf(z1.z, wv.z, fmaf(z1.y, wv.y, fmaf(z1.x, wv.x, a1[1][c]))));
        }
      }
      // relu + store Hb (one float4 per row)
      {
        float4 h0, h1;
        h0.x = fmaxf(a1[0][0], 0.f); h0.y = fmaxf(a1[0][1], 0.f);
        h0.z = fmaxf(a1[0][2], 0.f); h0.w = fmaxf(a1[0][3], 0.f);
        h1.x = fmaxf(a1[1][0], 0.f); h1.y = fmaxf(a1[1][1], 0.f);
        h1.z = fmaxf(a1[1][2], 0.f); h1.w = fmaxf(a1[1][3], 0.f);
        *(float4*)Hw0 = h0;
        *(float4*)Hw1 = h1;
      }
      __syncthreads();
      // ---- GEMM2 partial: accz[i][q] += sum_h Hb[row_i][h] * W2[8cg+q][hb*64+h] ----
      const float* w2b = w2l + (size_t)(cg << 3) * 256 + hb * 64;
      for (int h = 0; h < 64; h += 4) {
        float4 h0 = *(const float4*)(Hr0 + h);
        float4 h1 = *(const float4*)(Hr1 + h);
#pragma unroll
        for (int q = 0; q < 8; q++) {
          float4 wv = *(const float4*)(w2b + q * 256 + h);
          accz[0][q] = fmaf(h0.w, wv.w, fmaf(h0.z, wv.z, fmaf(h0.y, wv.y, fmaf(h0.x, wv.x, accz[0][q]))));
          accz[1][q] = fmaf(h1.w, wv.w, fmaf(h1.z, wv.z, fmaf(h1.y, wv.y, fmaf(h1.x, wv.x, accz[1][q]))));
        }
      }
      __syncthreads();
    }
    // Z[row_i][8cg + 0..7] += accz (thread-exclusive)
#pragma unroll
    for (int i = 0; i < 2; i++) {
      float* zr = Z + (r0 + 16 * i) * ZP + (cg << 3);
#pragma unroll
      for (int j = 0; j < 2; j++) {
        float4* pz = (float4*)(zr + 4 * j);
        float4 z = *pz;
        z.x += accz[i][4 * j + 0]; z.y += accz[i][4 * j + 1];
        z.z += accz[i][4 * j + 2]; z.w += accz[i][4 * j + 3];
        *pz = z;
      }
    }
    __syncthreads();
  }

  // ---- dist = ||rb - z||^2 : 8 threads per row, 16 floats each ----
  float* pd = Hb;              // Hb free now
  int* rwin = (int*)(Hb + 64);
  {
    int row = tx >> 3, seg = tx & 7;
    const float* rb = ws + WS_RB + b * 128 + (seg << 4);
    const float* zrow = Z + row * ZP + (seg << 4);
    float s = 0.f;
    for (int d = 0; d < 16; d += 4) {
      float4 zv = *(const float4*)(zrow + d);
      float4 rv = *(const float4*)(rb + d);
      float a0 = rv.x - zv.x, a1 = rv.y - zv.y, a2 = rv.z - zv.z, a3 = rv.w - zv.w;
      s += a0 * a0 + a1 * a1 + a2 * a2 + a3 * a3;
    }
    s += __shfl_xor(s, 1);    // commutative adds: all 8 lanes bit-identical
    s += __shfl_xor(s, 2);
    s += __shfl_xor(s, 4);
    if (seg == 0) pd[row] = s;
  }
  __syncthreads();
  if (tx < 64) {
    float v = pd[tx]; int idx = tx;
#pragma unroll
    for (int off = 32; off; off >>= 1) {
      float v2 = __shfl_xor(v, off);
      int   i2 = __shfl_xor(idx, off);
      if (v2 < v || (v2 == v && i2 < idx)) { v = v2; idx = i2; }
    }
    if (tx == 0) {
      ws[WS_BESTD + (b << 2) + t] = v;
      ((int*)ws)[WS_BESTI + (b << 2) + t] = k0 + idx;
      rwin[0] = idx;
    }
  }
  __syncthreads();
  if (tx < 32) {
    int rw = rwin[0];
    *(float4*)(ws + WS_BESTZ + (((b << 2) + t) << 7) + (tx << 2)) =
        *(const float4*)(Z + rw * ZP + (tx << 2));
  }
}

// ---------------- per-step update: pick tile winner, advance xhat ----------------
__global__ __launch_bounds__(128) void k_update(const float* __restrict__ x,
    float* __restrict__ ws, float* __restrict__ out, int m, int last)
{
  __shared__ int tsel;
  int tx = threadIdx.x, b = blockIdx.x;
  if (tx == 0) {
    float bv = ws[WS_BESTD + (b << 2)]; int bt = 0;
    for (int q = 1; q < 4; q++) {
      float v = ws[WS_BESTD + (b << 2) + q];
      if (v < bv) { bv = v; bt = q; }     // strict <: ties -> lowest k (tile order)
    }
    tsel = bt;
    int k = ((const int*)ws)[WS_BESTI + (b << 2) + bt];
    out[OUT_CODES + b * 8 + (m + 1)] = (float)k;
  }
  __syncthreads();
  int bt = tsel;
  float z  = ws[WS_BESTZ + (((b << 2) + bt) << 7) + tx];
  float xh = ws[WS_XHAT + b * 128 + tx] + z;
  ws[WS_XHAT + b * 128 + tx] = xh;
  ws[WS_RB   + b * 128 + tx] = x[b * 128 + tx] - xh;
  out[OUT_SIDE + (m + 1) * 131072 + b * 128 + tx] = xh;
  if (last) out[b * 128 + tx] = xh;       // final xhat == side[7]
}

extern "C" void kernel_launch(void* const* d_in, const int* in_sizes, int n_in,
                              void* d_out, int out_size, void* d_ws, size_t ws_size,
                              hipStream_t stream)
{
  const float* x   = (const float*)d_in[0];
  const float* cb0 = (const float*)d_in[1];
  const float* cbs = (const float*)d_in[2];
  const float* Wc  = (const float*)d_in[3];
  const float* bc  = (const float*)d_in[4];
  const float* W1  = (const float*)d_in[5];
  const float* W2  = (const float*)d_in[6];
  float* out = (float*)d_out;
  float* ws  = (float*)d_ws;

  k_step0<<<1024, 256, 0, stream>>>(x, cb0, ws, out);
  for (int m = 0; m < 7; m++) {
    k_prep<<<1280, 128, 0, stream>>>(cbs + m * 256 * 128, Wc + m * 128 * 256,
                                     bc + m * 128, ws);
    k_step<<<4096, 512, 0, stream>>>(W1, W2, ws, m);
    k_update<<<1024, 128, 0, stream>>>(x, ws, out, m, (m == 6) ? 1 : 0);
  }
}

// Round 7
// 2355.297 us; speedup vs baseline: 5.5544x; 5.5544x over previous
//
#include <hip/hip_runtime.h>

// QINCo round 7: MFMA fp16 hi/lo-split (Markidis) k_step.
// z*w ~= zh*wh + zh*wl + zl*wh with x_h=fp16(256x), x_l=fp16(256x - x_h):
// error ~2^-24 rel (fp32-level). 3x mfma_f32_32x32x16_f16 per product.
// Z and H live in LDS as hi/lo fp16 pairs [64][128] each (64KB -> 2 blk/CU).
// GEMM1 computes H^T (A=W1 global fp32 split on the fly, B=Z LDS) so C-layout
// reg quads are h-contiguous -> direct b64 stores in GEMM2's B layout.
// Shapes: D=128, M=8, K=256, L=2, H=256, BS=1024.
// Out layout (floats): xhat[1024*128] | codes[1024*8] | side[8][1024*128]

typedef _Float16 f16;
typedef f16 half4_t __attribute__((ext_vector_type(4)));
typedef f16 half8_t __attribute__((ext_vector_type(8)));
typedef float f32x16 __attribute__((ext_vector_type(16)));

#define OUT_CODES 131072
#define OUT_SIDE  139264

// ws float offsets
#define WS_XHAT  0          // [1024][128]
#define WS_RB    131072     // [1024][128]  r = x - xhat
#define WS_Y     262144     // [1024][128]  y = xhat @ Wx^T
#define WS_ZC    393216     // [256][128]   zc = cb + cb@Wz^T + bc
#define WS_BESTD 425984     // [1024][4]
#define WS_BESTI 430080     // [1024][4] (int)
#define WS_BESTZ 434176     // [1024][4][128]

__device__ __forceinline__ f32x16 mfma_f16(half8_t a, half8_t b, f32x16 c) {
  return __builtin_amdgcn_mfma_f32_32x32x16_f16(a, b, c, 0, 0, 0);
}

// split 8 fp32 into scaled (x256) fp16 hi/lo
__device__ __forceinline__ void split8s(float4 p, float4 q, half8_t& hi, half8_t& lo) {
  float s[8] = {p.x, p.y, p.z, p.w, q.x, q.y, q.z, q.w};
#pragma unroll
  for (int i = 0; i < 8; i++) {
    float v = s[i] * 256.f;
    f16 h = (f16)v;
    hi[i] = h;
    lo[i] = (f16)(v - (float)h);
  }
}

// B-fragment read: 8 logical halfs [d0..d0+8) of row m, column-rotated LDS.
__device__ __forceinline__ half8_t ldsB(const f16* base, int m, int d0) {
  int rot = (m & 15) << 2;
  const f16* r = base + m * 128;
  half4_t a = *(const half4_t*)(r + ((d0 + rot) & 127));
  half4_t b = *(const half4_t*)(r + ((d0 + 4 + rot) & 127));
  return __builtin_shufflevector(a, b, 0, 1, 2, 3, 4, 5, 6, 7);
}

// ---------------- step 0: nearest codebook0 row ----------------
__global__ __launch_bounds__(256) void k_step0(const float* __restrict__ x,
    const float* __restrict__ cb0, float* __restrict__ ws, float* __restrict__ out)
{
  __shared__ float xs[128];
  __shared__ float redv[4];
  __shared__ int   redi[4];
  __shared__ int   kwin;
  int tx = threadIdx.x, b = blockIdx.x;
  if (tx < 128) xs[tx] = x[b * 128 + tx];
  __syncthreads();
  const float* c = cb0 + tx * 128;   // k = tx
  float s = 0.f;
  for (int d = 0; d < 128; d += 4) {
    float4 cv = *(const float4*)(c + d);
    float4 xv = *(const float4*)(xs + d);
    float a0 = xv.x - cv.x, a1 = xv.y - cv.y, a2 = xv.z - cv.z, a3 = xv.w - cv.w;
    s += a0 * a0 + a1 * a1 + a2 * a2 + a3 * a3;
  }
  float v = s; int idx = tx;
  for (int off = 32; off; off >>= 1) {
    float v2 = __shfl_xor(v, off);
    int   i2 = __shfl_xor(idx, off);
    if (v2 < v || (v2 == v && i2 < idx)) { v = v2; idx = i2; }
  }
  if ((tx & 63) == 0) { redv[tx >> 6] = v; redi[tx >> 6] = idx; }
  __syncthreads();
  if (tx == 0) {
    float bv = redv[0]; int bi = redi[0];
    for (int w = 1; w < 4; w++)
      if (redv[w] < bv || (redv[w] == bv && redi[w] < bi)) { bv = redv[w]; bi = redi[w]; }
    kwin = bi;
    out[OUT_CODES + b * 8] = (float)bi;
  }
  __syncthreads();
  int k = kwin;
  if (tx < 128) {
    float xh = cb0[k * 128 + tx];
    ws[WS_XHAT + b * 128 + tx] = xh;
    ws[WS_RB   + b * 128 + tx] = xs[tx] - xh;
    out[OUT_SIDE + b * 128 + tx] = xh;   // side[0]
  }
}

// ---------------- per-step prep: zc and y (fp32) ----------------
__global__ __launch_bounds__(128) void k_prep(const float* __restrict__ cb,
    const float* __restrict__ Wc, const float* __restrict__ bcm, float* __restrict__ ws)
{
  __shared__ float row[128];
  int tx = threadIdx.x, blk = blockIdx.x;
  if (blk < 256) {          // zc[k][i] = cb[k][i] + sum_d cb[k][d]*Wc[i][d] + bc[i]
    row[tx] = cb[blk * 128 + tx];
    __syncthreads();
    const float* wrow = Wc + tx * 256;
    float s = 0.f;
    for (int d = 0; d < 128; d += 4) {
      float4 wv = *(const float4*)(wrow + d);
      float4 zv = *(const float4*)(row + d);
      s += wv.x * zv.x + wv.y * zv.y + wv.z * zv.z + wv.w * zv.w;
    }
    ws[WS_ZC + blk * 128 + tx] = row[tx] + s + bcm[tx];
  } else {                  // y[b][i] = sum_d xhat[b][d]*Wc[i][128+d]
    int b = blk - 256;
    row[tx] = ws[WS_XHAT + b * 128 + tx];
    __syncthreads();
    const float* wrow = Wc + tx * 256 + 128;
    float s = 0.f;
    for (int d = 0; d < 128; d += 4) {
      float4 wv = *(const float4*)(wrow + d);
      float4 zv = *(const float4*)(row + d);
      s += wv.x * zv.x + wv.y * zv.y + wv.z * zv.z + wv.w * zv.w;
    }
    ws[WS_Y + b * 128 + tx] = s;
  }
}

// ---------------- main step kernel: 64 candidates of one b, MFMA ----------------
// 256 threads = 4 waves. lane: col = lane&31, koct = lane>>5.
// GEMM1 per h-half hf: wave w -> H^T rows h_local [32w,32w+32), C[h][m].
//   A = W1[h][d] (global fp32, split x256 on the fly), B = Z[m][d] (LDS hi/lo).
// GEMM2 (K = h, accumulated over both halves): wave w -> out rows d [32w,+32).
//   A = W2[d][h] (global), B = H[m][h] (LDS hi/lo).
// Epilogues use C/D layout col=lane&31, row=(reg&3)+8*(reg>>2)+4*(lane>>5).
__global__ __launch_bounds__(256, 2) void k_step(const float* __restrict__ W1g,
    const float* __restrict__ W2g, float* __restrict__ ws, int sm)
{
  __shared__ f16 Zh[8192];
  __shared__ f16 Zl[8192];
  __shared__ f16 Hh[8192];
  __shared__ f16 Hl[8192];
  int tx = threadIdx.x;
  int lane = tx & 63, w = tx >> 6;
  int col = lane & 31, koct = lane >> 5;
  int b = blockIdx.x >> 2, t = blockIdx.x & 3, k0 = t << 6;

  // ---- init Z = zc[k0+m] + y[b], split x256 into Zh/Zl ----
  {
    const float* zc = ws + WS_ZC + k0 * 128;
    const float* y  = ws + WS_Y + b * 128;
    for (int idx = tx; idx < 1024; idx += 256) {
      int m = idx & 63, d0 = (idx >> 6) << 3;
      float4 a  = *(const float4*)(zc + m * 128 + d0);
      float4 bb = *(const float4*)(zc + m * 128 + d0 + 4);
      float4 ya = *(const float4*)(y + d0);
      float4 yb = *(const float4*)(y + d0 + 4);
      float sv[8] = {a.x + ya.x, a.y + ya.y, a.z + ya.z, a.w + ya.w,
                     bb.x + yb.x, bb.y + yb.y, bb.z + yb.z, bb.w + yb.w};
      int rot = (m & 15) << 2;
      int c0 = (d0 + rot) & 127, c1 = (d0 + 4 + rot) & 127;
      half4_t h0, l0, h1, l1;
#pragma unroll
      for (int j = 0; j < 4; j++) {
        float v = sv[j] * 256.f;
        f16 h = (f16)v; h0[j] = h; l0[j] = (f16)(v - (float)h);
        v = sv[j + 4] * 256.f;
        h = (f16)v; h1[j] = h; l1[j] = (f16)(v - (float)h);
      }
      *(half4_t*)(Zh + m * 128 + c0) = h0;
      *(half4_t*)(Zl + m * 128 + c0) = l0;
      *(half4_t*)(Zh + m * 128 + c1) = h1;
      *(half4_t*)(Zl + m * 128 + c1) = l1;
    }
  }
  __syncthreads();

  for (int l = 0; l < 2; l++) {
    const float* w1l = W1g + (size_t)(sm * 2 + l) * (256 * 128);
    const float* w2l = W2g + (size_t)(sm * 2 + l) * (128 * 256);
    f32x16 acc2[2];
#pragma unroll
    for (int i = 0; i < 16; i++) { acc2[0][i] = 0.f; acc2[1][i] = 0.f; }

#pragma unroll
    for (int hf = 0; hf < 2; hf++) {
      // ---- GEMM1: acc1[mt] = H^T tile (h rows 32w..+32, m cols 32mt..+32) ----
      f32x16 acc1[2];
#pragma unroll
      for (int i = 0; i < 16; i++) { acc1[0][i] = 0.f; acc1[1][i] = 0.f; }
      const float* w1base = w1l + (size_t)(hf * 128 + (w << 5) + col) * 128 + (koct << 3);
#pragma unroll
      for (int kc = 0; kc < 8; kc++) {
        int d0 = kc << 4;
        float4 p = *(const float4*)(w1base + d0);
        float4 q = *(const float4*)(w1base + d0 + 4);
        half8_t ah, al; split8s(p, q, ah, al);
        int dd = d0 + (koct << 3);
        half8_t bh0 = ldsB(Zh, col, dd);
        half8_t bl0 = ldsB(Zl, col, dd);
        acc1[0] = mfma_f16(ah, bh0, acc1[0]);
        acc1[0] = mfma_f16(al, bh0, acc1[0]);
        acc1[0] = mfma_f16(ah, bl0, acc1[0]);
        half8_t bh1 = ldsB(Zh, col + 32, dd);
        half8_t bl1 = ldsB(Zl, col + 32, dd);
        acc1[1] = mfma_f16(ah, bh1, acc1[1]);
        acc1[1] = mfma_f16(al, bh1, acc1[1]);
        acc1[1] = mfma_f16(ah, bl1, acc1[1]);
      }
      // relu, rescale to 256*h, split, store Hh/Hl (h-contiguous quads)
#pragma unroll
      for (int mt = 0; mt < 2; mt++) {
        int mrow = (mt << 5) + col;
        int rot = (mrow & 15) << 2;
        f16* hhr = Hh + mrow * 128;
        f16* hlr = Hl + mrow * 128;
#pragma unroll
        for (int qd = 0; qd < 4; qd++) {
          half4_t hv, lv;
#pragma unroll
          for (int j = 0; j < 4; j++) {
            float tv = fmaxf(acc1[mt][(qd << 2) + j], 0.f) * 0.00390625f; // acc*2^-16*256
            f16 h = (f16)tv; hv[j] = h; lv[j] = (f16)(tv - (float)h);
          }
          int c = (((w << 5) + (qd << 3) + (koct << 2)) + rot) & 127;
          *(half4_t*)(hhr + c) = hv;
          *(half4_t*)(hlr + c) = lv;
        }
      }
      __syncthreads();
      // ---- GEMM2 partial over this h-half: acc2[mt] += W2 x H^T ----
      const float* w2base = w2l + (size_t)((w << 5) + col) * 256 + hf * 128 + (koct << 3);
#pragma unroll
      for (int kc = 0; kc < 8; kc++) {
        int h0 = kc << 4;
        float4 p = *(const float4*)(w2base + h0);
        float4 q = *(const float4*)(w2base + h0 + 4);
        half8_t ah, al; split8s(p, q, ah, al);
        int hh0 = h0 + (koct << 3);
        half8_t bh0 = ldsB(Hh, col, hh0);
        half8_t bl0 = ldsB(Hl, col, hh0);
        acc2[0] = mfma_f16(ah, bh0, acc2[0]);
        acc2[0] = mfma_f16(al, bh0, acc2[0]);
        acc2[0] = mfma_f16(ah, bl0, acc2[0]);
        half8_t bh1 = ldsB(Hh, col + 32, hh0);
        half8_t bl1 = ldsB(Hl, col + 32, hh0);
        acc2[1] = mfma_f16(ah, bh1, acc2[1]);
        acc2[1] = mfma_f16(al, bh1, acc2[1]);
        acc2[1] = mfma_f16(ah, bl1, acc2[1]);
      }
      __syncthreads();
    }
    // ---- epilogue2: Z[m][d] += acc2*2^-16 (in scaled units: += acc2*2^-8) ----
#pragma unroll
    for (int mt = 0; mt < 2; mt++) {
      int mrow = (mt << 5) + col;
      int rot = (mrow & 15) << 2;
      f16* zhr = Zh + mrow * 128;
      f16* zlr = Zl + mrow * 128;
#pragma unroll
      for (int qd = 0; qd < 4; qd++) {
        int c = (((w << 5) + (qd << 3) + (koct << 2)) + rot) & 127;
        half4_t zh = *(half4_t*)(zhr + c);
        half4_t zl = *(half4_t*)(zlr + c);
#pragma unroll
        for (int j = 0; j < 4; j++) {
          float zs = (float)zh[j] + (float)zl[j];
          zs += acc2[mt][(qd << 2) + j] * 0.00390625f;
          f16 h = (f16)zs; zh[j] = h; zl[j] = (f16)(zs - (float)h);
        }
        *(half4_t*)(zhr + c) = zh;
        *(half4_t*)(zlr + c) = zl;
      }
    }
    __syncthreads();
  }

  // ---- dist = ||rb - z||^2 over 64 rows (4 threads/row, 32 d each) ----
  float* pd = (float*)Hh;          // H buffers free now
  int* rwin = (int*)Hh + 64;
  {
    int row = tx >> 2, seg = tx & 3;
    const float* rb = ws + WS_RB + b * 128 + (seg << 5);
    int rot = (row & 15) << 2;
    const f16* zhr = Zh + row * 128;
    const f16* zlr = Zl + row * 128;
    float s = 0.f;
#pragma unroll
    for (int o = 0; o < 4; o++) {
      int d = (seg << 5) + (o << 3);
      int c0 = (d + rot) & 127, c1 = (d + 4 + rot) & 127;
      half4_t zh0 = *(const half4_t*)(zhr + c0);
      half4_t zl0 = *(const half4_t*)(zlr + c0);
      half4_t zh1 = *(const half4_t*)(zhr + c1);
      half4_t zl1 = *(const half4_t*)(zlr + c1);
      float4 r0 = *(const float4*)(rb + (o << 3));
      float4 r1 = *(const float4*)(rb + (o << 3) + 4);
      float z, dlt;
      z = ((float)zh0[0] + (float)zl0[0]) * 0.00390625f; dlt = r0.x - z; s += dlt * dlt;
      z = ((float)zh0[1] + (float)zl0[1]) * 0.00390625f; dlt = r0.y - z; s += dlt * dlt;
      z = ((float)zh0[2] + (float)zl0[2]) * 0.00390625f; dlt = r0.z - z; s += dlt * dlt;
      z = ((float)zh0[3] + (float)zl0[3]) * 0.00390625f; dlt = r0.w - z; s += dlt * dlt;
      z = ((float)zh1[0] + (float)zl1[0]) * 0.00390625f; dlt = r1.x - z; s += dlt * dlt;
      z = ((float)zh1[1] + (float)zl1[1]) * 0.00390625f; dlt = r1.y - z; s += dlt * dlt;
      z = ((float)zh1[2] + (float)zl1[2]) * 0.00390625f; dlt = r1.z - z; s += dlt * dlt;
      z = ((float)zh1[3] + (float)zl1[3]) * 0.00390625f; dlt = r1.w - z; s += dlt * dlt;
    }
    s += __shfl_xor(s, 1);   // all 4 lanes of a row end bit-identical
    s += __shfl_xor(s, 2);
    if (seg == 0) pd[row] = s;
  }
  __syncthreads();
  if (tx < 64) {
    float v = pd[tx]; int idx = tx;
#pragma unroll
    for (int off = 32; off; off >>= 1) {
      float v2 = __shfl_xor(v, off);
      int   i2 = __shfl_xor(idx, off);
      if (v2 < v || (v2 == v && i2 < idx)) { v = v2; idx = i2; }
    }
    if (tx == 0) {
      ws[WS_BESTD + (b << 2) + t] = v;
      ((int*)ws)[WS_BESTI + (b << 2) + t] = k0 + idx;
      rwin[0] = idx;
    }
  }
  __syncthreads();
  if (tx < 32) {
    int rw = rwin[0];
    int c = ((tx << 2) + ((rw & 15) << 2)) & 127;
    half4_t zh = *(const half4_t*)(Zh + rw * 128 + c);
    half4_t zl = *(const half4_t*)(Zl + rw * 128 + c);
    float4 z;
    z.x = ((float)zh[0] + (float)zl[0]) * 0.00390625f;
    z.y = ((float)zh[1] + (float)zl[1]) * 0.00390625f;
    z.z = ((float)zh[2] + (float)zl[2]) * 0.00390625f;
    z.w = ((float)zh[3] + (float)zl[3]) * 0.00390625f;
    *(float4*)(ws + WS_BESTZ + (((b << 2) + t) << 7) + (tx << 2)) = z;
  }
}

// ---------------- per-step update: pick tile winner, advance xhat ----------------
__global__ __launch_bounds__(128) void k_update(const float* __restrict__ x,
    float* __restrict__ ws, float* __restrict__ out, int m, int last)
{
  __shared__ int tsel;
  int tx = threadIdx.x, b = blockIdx.x;
  if (tx == 0) {
    float bv = ws[WS_BESTD + (b << 2)]; int bt = 0;
    for (int q = 1; q < 4; q++) {
      float v = ws[WS_BESTD + (b << 2) + q];
      if (v < bv) { bv = v; bt = q; }     // strict <: ties -> lowest k (tile order)
    }
    tsel = bt;
    int k = ((const int*)ws)[WS_BESTI + (b << 2) + bt];
    out[OUT_CODES + b * 8 + (m + 1)] = (float)k;
  }
  __syncthreads();
  int bt = tsel;
  float z  = ws[WS_BESTZ + (((b << 2) + bt) << 7) + tx];
  float xh = ws[WS_XHAT + b * 128 + tx] + z;
  ws[WS_XHAT + b * 128 + tx] = xh;
  ws[WS_RB   + b * 128 + tx] = x[b * 128 + tx] - xh;
  out[OUT_SIDE + (m + 1) * 131072 + b * 128 + tx] = xh;
  if (last) out[b * 128 + tx] = xh;       // final xhat == side[7]
}

extern "C" void kernel_launch(void* const* d_in, const int* in_sizes, int n_in,
                              void* d_out, int out_size, void* d_ws, size_t ws_size,
                              hipStream_t stream)
{
  const float* x   = (const float*)d_in[0];
  const float* cb0 = (const float*)d_in[1];
  const float* cbs = (const float*)d_in[2];
  const float* Wc  = (const float*)d_in[3];
  const float* bc  = (const float*)d_in[4];
  const float* W1  = (const float*)d_in[5];
  const float* W2  = (const float*)d_in[6];
  float* out = (float*)d_out;
  float* ws  = (float*)d_ws;

  k_step0<<<1024, 256, 0, stream>>>(x, cb0, ws, out);
  for (int m = 0; m < 7; m++) {
    k_prep<<<1280, 128, 0, stream>>>(cbs + m * 256 * 128, Wc + m * 128 * 256,
                                     bc + m * 128, ws);
    k_step<<<4096, 256, 0, stream>>>(W1, W2, ws, m);
    k_update<<<1024, 128, 0, stream>>>(x, ws, out, m, (m == 6) ? 1 : 0);
  }
}